// Round 13
// baseline (29.409 us; speedup 1.0000x reference)
//
#include <hip/hip_runtime.h>
#include <math.h>

#define NB 16
#define NQ 900
#define NQP 928             // padded teacher count (58*16)
#define NHALF 464           // slot-B offset
#define NC 80
#define EPSV 1e-7f
#define IOU_THR 0.1f
#define SPB 16              // students per block
#define CHB 57              // blocks per batch (57*16 = 912 >= 900)
#define NBLK (NB * CHB)     // 912

__device__ __forceinline__ float sigm(float x) { return 1.0f / (1.0f + __expf(-x)); }

// ---- K1: per-(b, 16 students): IoU argmax (16-lane split, 2 ILP slots) + BCE/conf ----
__global__ __launch_bounds__(256) void k_main(
    const float* __restrict__ s_logits,
    const float* __restrict__ s_boxes,
    const float* __restrict__ t_logits,
    const float* __restrict__ t_boxes,
    int*    __restrict__ g_idx,     // [NB*NQ] argmax teacher index (plain store)
    float*  __restrict__ g_v,       // [NB*NQ] flag-gated 5*l1+2*(1-giou), else 0
    float2* __restrict__ g_part)    // [NBLK]  (bce_sum, conf_any)
{
    __shared__ float4 tcor[NQP];    // x1, x2, y1, y2 (pad: impossible boxes -> iou 0)
    __shared__ float2 apair[NHALF]; // (area[t], area[t+464]) -> one ds_read_b64 / iter
    __shared__ int    lidx[SPB];
    __shared__ float  sconf0;
    __shared__ float2 sres[SPB];    // per-row (bce_mean, conf)

    const int bx  = blockIdx.x;     // 0..56
    const int b   = blockIdx.y;     // 0..15
    const int tid = threadIdx.x;

    // stage teacher boxes of batch b (padded to 928); areas into paired layout
    const float4* tb = (const float4*)(t_boxes + b * NQ * 4);
    for (int i = tid; i < NQP; i += 256) {
        float ar;
        if (i < NQ) {
            float4 t = tb[i];
            float hw = t.z * 0.5f, hh = t.w * 0.5f;
            tcor[i] = make_float4(t.x - hw, t.x + hw, t.y - hh, t.y + hh);
            ar = t.z * t.w;
        } else {
            tcor[i] = make_float4(2e9f, -2e9f, 2e9f, -2e9f);  // inter == 0 exactly
            ar = 1.0f;
        }
        if (i < NHALF) apair[i].x = ar;
        else           apair[i - NHALF].y = ar;
    }
    // conf0[b] (one wave; redundant per block but cheap)
    if (tid < 64) {
        const float* tl = t_logits + b * NQ * NC;   // teacher row 0 of batch b
        float m = tl[tid];
        if (tid < NC - 64) m = fmaxf(m, tl[tid + 64]);
        for (int s = 32; s >= 1; s >>= 1) m = fmaxf(m, __shfl_xor(m, s, 64));
        if (tid == 0) sconf0 = (sigm(m) > 0.2f) ? 1.0f : 0.0f;
    }
    __syncthreads();

    // ---- argmax IoU over 900(+pad) teachers; 16 lanes per student, 2 ILP slots ----
    const int s  = tid >> 4;        // 0..15
    const int tc = tid & 15;        // teacher phase
    const int sq = bx * SPB + s;
    const bool act = (sq < NQ);
    float4 sb = make_float4(0.f, 0.f, 0.f, 0.f);
    if (act) sb = ((const float4*)(s_boxes + b * NQ * 4))[sq];
    const float shw = sb.z * 0.5f, shh = sb.w * 0.5f;
    const float sx1 = sb.x - shw, sx2 = sb.x + shw;
    const float sy1 = sb.y - shh, sy2 = sb.y + shh;
    const float sarea = sb.z * sb.w;

    float bvA = -1.0f, bvB = -1.0f; int biA = 0, biB = 0;
    #pragma unroll 4
    for (int i = 0; i < 29; ++i) {
        const int ta = tc + (i << 4);           // [0, 464)
        const float2 ap = apair[ta];            // both slots' areas, one b64
        {   // slot A: t = ta
            float4 c = tcor[ta];
            float iw = fminf(sx2, c.y) - fmaxf(sx1, c.x);
            float ih = fminf(sy2, c.w) - fmaxf(sy1, c.z);
            float inter = fmaxf(iw, 0.0f) * fmaxf(ih, 0.0f);
            float uni = sarea + ap.x - inter + EPSV;
            float iou = inter * __frcp_rn(uni);
            if (iou > bvA) { bvA = iou; biA = ta; }   // strictly greater
        }
        {   // slot B: t = ta + 464 (indices all > slot A's)
            int t = ta + NHALF;
            float4 c = tcor[t];
            float iw = fminf(sx2, c.y) - fmaxf(sx1, c.x);
            float ih = fminf(sy2, c.w) - fmaxf(sy1, c.z);
            float inter = fmaxf(iw, 0.0f) * fmaxf(ih, 0.0f);
            float uni = sarea + ap.y - inter + EPSV;
            float iou = inter * __frcp_rn(uni);
            if (iou > bvB) { bvB = iou; biB = t; }    // strictly greater
        }
    }
    float best = bvA; int bidx = biA;
    if (bvB > best) { best = bvB; bidx = biB; }       // B's indices all greater
    // combine 16 phases; ties -> lower index (argmax first-occurrence)
    for (int m = 1; m <= 8; m <<= 1) {
        float ov = __shfl_xor(best, m, 64);
        int   oi = __shfl_xor(bidx, m, 64);
        if (ov > best || (ov == best && oi < bidx)) { best = ov; bidx = oi; }
    }
    if (act && tc == 0) {
        int o = b * NQ + sq;
        lidx[s]  = bidx;
        g_idx[o] = bidx;                        // plain store; kernel boundary = coherence
        // L1 and (1 - GIoU) vs teacher box 0 (exact divides like ref)
        float4 t0 = tb[0];
        float4 c  = tcor[0];
        float iw = fminf(sx2, c.y) - fmaxf(sx1, c.x);
        float ih = fminf(sy2, c.w) - fmaxf(sy1, c.z);
        float inter = fmaxf(iw, 0.0f) * fmaxf(ih, 0.0f);
        float uni = sarea + t0.z * t0.w - inter + EPSV;
        float iou = inter / uni;
        float cw = fmaxf(sx2, c.y) - fminf(sx1, c.x);
        float ch = fmaxf(sy2, c.w) - fminf(sy1, c.z);
        float carea = cw * ch + EPSV;
        float giou1 = 1.0f - (iou - (carea - uni) / carea);
        float l1 = fabsf(sb.x - t0.x) + fabsf(sb.y - t0.y) +
                   fabsf(sb.z - t0.z) + fabsf(sb.w - t0.w);
        float v = 0.0f;
        if (sconf0 > 0.0f && best > IOU_THR) v = 5.0f * l1 + 2.0f * giou1;
        g_v[o] = v;
    }
    __syncthreads();

    // ---- BCE + conf: 16-lane group per row; float4 + scalar loads ----
    const int wv  = tid >> 6, lane = tid & 63;
    const int grp = lane >> 4, tc2 = lane & 15;
    const int s2  = wv * 4 + grp;              // 0..15
    const int sq2 = bx * SPB + s2;
    if (sq2 < NQ) {
        int row = b * NQ + sq2;
        int j   = lidx[s2];                    // flat idx -> batch-0 teacher row (ref quirk)
        const float* srow = s_logits + row * NC;
        const float* trow = t_logits + row * NC;
        const float* grow = t_logits + j * NC;
        float4 svv = *(const float4*)(srow + tc2 * 4);
        float4 tvv = *(const float4*)(trow + tc2 * 4);
        float4 gvv = *(const float4*)(grow + tc2 * 4);
        float  s4 = srow[64 + tc2];
        float  t4 = trow[64 + tc2];
        float  g4 = grow[64 + tc2];
        float bce = 0.f;
        {
            float se[5] = {svv.x, svv.y, svv.z, svv.w, s4};
            float ge[5] = {gvv.x, gvv.y, gvv.z, gvv.w, g4};
            #pragma unroll
            for (int e = 0; e < 5; ++e) {
                float s0 = se[e], g0 = ge[e];
                bce += fmaxf(s0, 0.f) + __logf(1.0f + __expf(-fabsf(s0)))
                     - s0 * __builtin_amdgcn_rcpf(1.0f + __expf(-g0));
            }
        }
        float tmax = fmaxf(fmaxf(fmaxf(tvv.x, tvv.y), fmaxf(tvv.z, tvv.w)), t4);
        for (int m = 8; m >= 1; m >>= 1) {
            bce  += __shfl_xor(bce, m, 64);
            tmax  = fmaxf(tmax, __shfl_xor(tmax, m, 64));
        }
        if (tc2 == 0)
            sres[s2] = make_float2(bce * (1.0f / (float)NC),
                                   (sigm(tmax) > 0.2f) ? 1.0f : 0.0f);
    }
    __syncthreads();
    if (tid < 64) {
        float bs = 0.f, ca = 0.f;
        if (tid < SPB) { float2 p = sres[tid]; bs = p.x; ca = p.y; }
        for (int m = 32; m >= 1; m >>= 1) {
            bs += __shfl_xor(bs, m, 64);
            ca  = fmaxf(ca, __shfl_xor(ca, m, 64));
        }
        if (tid == 0) g_part[b * CHB + bx] = make_float2(bs, ca);
    }
}

// ---- K2: single block — LDS histogram of g_idx, then coalesced cnt·v dot ----
__global__ __launch_bounds__(1024) void k_final(
    const int*    __restrict__ g_idx,
    const float*  __restrict__ g_v,
    const float2* __restrict__ g_part,
    const int*    __restrict__ tn_p,
    float* __restrict__ out)
{
    __shared__ int   cnt[NB * NQ];   // 57.6 KB
    __shared__ float rb[16], rv[16], rc[16];
    const int tid = threadIdx.x;

    for (int i = tid; i < NB * NQ; i += 1024) cnt[i] = 0;
    __syncthreads();
    #pragma unroll
    for (int k = 0; k < 15; ++k) {
        int i = tid + k * 1024;
        if (i < NB * NQ) {
            int j = g_idx[i];                  // coalesced read
            int b = i / NQ;
            atomicAdd(&cnt[b * NQ + j], 1);    // LDS atomic, deterministic int sum
        }
    }
    __syncthreads();

    float bs = 0.f, ca = 0.f;
    if (tid < NBLK) { float2 p = g_part[tid]; bs = p.x; ca = p.y; }
    float vs = 0.f;
    #pragma unroll
    for (int k = 0; k < 15; ++k) {
        int i = tid + k * 1024;
        if (i < NB * NQ) vs += (float)cnt[i] * g_v[i];   // coalesced, fixed order
    }
    const int wv = tid >> 6, lane = tid & 63;
    for (int m = 32; m >= 1; m >>= 1) {
        bs += __shfl_xor(bs, m, 64);
        vs += __shfl_xor(vs, m, 64);
        ca  = fmaxf(ca, __shfl_xor(ca, m, 64));
    }
    if (lane == 0) { rb[wv] = bs; rv[wv] = vs; rc[wv] = ca; }
    __syncthreads();
    if (tid == 0) {
        float sb = 0.f, sv = 0.f, sc = 0.f;
        for (int k = 0; k < 16; ++k) { sb += rb[k]; sv += rv[k]; sc = fmaxf(sc, rc[k]); }
        float tn = (float)tn_p[0];
        out[0] = (sc > 0.f) ? (sv + sb) / tn : 0.0f;
    }
}

extern "C" void kernel_launch(void* const* d_in, const int* in_sizes, int n_in,
                              void* d_out, int out_size, void* d_ws, size_t ws_size,
                              hipStream_t stream) {
    const float* s_logits = (const float*)d_in[0];
    const float* s_boxes  = (const float*)d_in[1];
    const float* t_logits = (const float*)d_in[2];
    const float* t_boxes  = (const float*)d_in[3];
    const int*   tn       = (const int*)d_in[4];
    float* out = (float*)d_out;

    char* ws = (char*)d_ws;
    int*    g_idx  = (int*)(ws);              // 14400 i32
    float*  g_v    = (float*)(ws + 57600);    // 14400 f32
    float2* g_part = (float2*)(ws + 115200);  // 912 float2

    k_main<<<dim3(CHB, NB), 256, 0, stream>>>(s_logits, s_boxes, t_logits, t_boxes,
                                              g_idx, g_v, g_part);
    k_final<<<1, 1024, 0, stream>>>(g_idx, g_v, g_part, tn, out);
}

// Round 14
// 27.800 us; speedup vs baseline: 1.0579x; 1.0579x over previous
//
#include <hip/hip_runtime.h>
#include <math.h>

#define NB 16
#define NQ 900
#define NQP 928             // padded teacher count (58*16)
#define NHALF 464           // slot-B offset
#define NC 80
#define EPSV 1e-7f
#define IOU_THR 0.1f
#define SPB 16              // students per block
#define CHB 57              // blocks per batch (57*16 = 912 >= 900)
#define NBLK (NB * CHB)     // 912

__device__ __forceinline__ float sigm(float x) { return 1.0f / (1.0f + __expf(-x)); }

// ---- K1: per-(b, 16 students): IoU argmax (16-lane split, 2 ILP slots) + BCE/conf ----
__global__ __launch_bounds__(256) void k_main(
    const float* __restrict__ s_logits,
    const float* __restrict__ s_boxes,
    const float* __restrict__ t_logits,
    const float* __restrict__ t_boxes,
    int*    __restrict__ g_idx,     // [NB*NQ] argmax teacher index (plain store)
    float*  __restrict__ g_v,       // [NB*NQ] flag-gated 5*l1+2*(1-giou), else 0
    float2* __restrict__ g_part)    // [NBLK]  (bce_sum, conf_any)
{
    __shared__ float4 tcor[NQP];    // x1, x2, y1, y2 (pad: impossible boxes -> iou 0)
    __shared__ float2 apair[NHALF]; // (area[t], area[t+464]) -> one ds_read_b64 / iter
    __shared__ int    lidx[SPB];
    __shared__ float  sconf0;
    __shared__ float2 sres[SPB];    // per-row (bce_mean, conf)

    const int bx  = blockIdx.x;     // 0..56
    const int b   = blockIdx.y;     // 0..15
    const int tid = threadIdx.x;

    // stage teacher boxes of batch b (padded to 928); areas into paired layout
    const float4* tb = (const float4*)(t_boxes + b * NQ * 4);
    for (int i = tid; i < NQP; i += 256) {
        float ar;
        if (i < NQ) {
            float4 t = tb[i];
            float hw = t.z * 0.5f, hh = t.w * 0.5f;
            tcor[i] = make_float4(t.x - hw, t.x + hw, t.y - hh, t.y + hh);
            ar = t.z * t.w;
        } else {
            tcor[i] = make_float4(2e9f, -2e9f, 2e9f, -2e9f);  // inter == 0 exactly
            ar = 1.0f;
        }
        if (i < NHALF) apair[i].x = ar;
        else           apair[i - NHALF].y = ar;
    }
    // conf0[b] (one wave; redundant per block but cheap)
    if (tid < 64) {
        const float* tl = t_logits + b * NQ * NC;   // teacher row 0 of batch b
        float m = tl[tid];
        if (tid < NC - 64) m = fmaxf(m, tl[tid + 64]);
        for (int s = 32; s >= 1; s >>= 1) m = fmaxf(m, __shfl_xor(m, s, 64));
        if (tid == 0) sconf0 = (sigm(m) > 0.2f) ? 1.0f : 0.0f;
    }
    __syncthreads();

    // ---- argmax IoU over 900(+pad) teachers; 16 lanes per student, 2 ILP slots ----
    const int s  = tid >> 4;        // 0..15
    const int tc = tid & 15;        // teacher phase
    const int sq = bx * SPB + s;
    const bool act = (sq < NQ);
    float4 sb = make_float4(0.f, 0.f, 0.f, 0.f);
    if (act) sb = ((const float4*)(s_boxes + b * NQ * 4))[sq];
    const float shw = sb.z * 0.5f, shh = sb.w * 0.5f;
    const float sx1 = sb.x - shw, sx2 = sb.x + shw;
    const float sy1 = sb.y - shh, sy2 = sb.y + shh;
    const float sarea = sb.z * sb.w;

    float bvA = -1.0f, bvB = -1.0f; int biA = 0, biB = 0;
    #pragma unroll 4
    for (int i = 0; i < 29; ++i) {
        const int ta = tc + (i << 4);           // [0, 464)
        const float2 ap = apair[ta];            // both slots' areas, one b64
        {   // slot A: t = ta
            float4 c = tcor[ta];
            float iw = fminf(sx2, c.y) - fmaxf(sx1, c.x);
            float ih = fminf(sy2, c.w) - fmaxf(sy1, c.z);
            float inter = fmaxf(iw, 0.0f) * fmaxf(ih, 0.0f);
            float uni = sarea + ap.x - inter + EPSV;
            float iou = inter * __frcp_rn(uni);
            if (iou > bvA) { bvA = iou; biA = ta; }   // strictly greater
        }
        {   // slot B: t = ta + 464 (indices all > slot A's)
            int t = ta + NHALF;
            float4 c = tcor[t];
            float iw = fminf(sx2, c.y) - fmaxf(sx1, c.x);
            float ih = fminf(sy2, c.w) - fmaxf(sy1, c.z);
            float inter = fmaxf(iw, 0.0f) * fmaxf(ih, 0.0f);
            float uni = sarea + ap.y - inter + EPSV;
            float iou = inter * __frcp_rn(uni);
            if (iou > bvB) { bvB = iou; biB = t; }    // strictly greater
        }
    }
    float best = bvA; int bidx = biA;
    if (bvB > best) { best = bvB; bidx = biB; }       // B's indices all greater
    // combine 16 phases; ties -> lower index (argmax first-occurrence)
    for (int m = 1; m <= 8; m <<= 1) {
        float ov = __shfl_xor(best, m, 64);
        int   oi = __shfl_xor(bidx, m, 64);
        if (ov > best || (ov == best && oi < bidx)) { best = ov; bidx = oi; }
    }
    if (act && tc == 0) {
        int o = b * NQ + sq;
        lidx[s]  = bidx;
        g_idx[o] = bidx;                        // plain store; kernel boundary = coherence
        // L1 and (1 - GIoU) vs teacher box 0 (exact divides like ref)
        float4 t0 = tb[0];
        float4 c  = tcor[0];
        float iw = fminf(sx2, c.y) - fmaxf(sx1, c.x);
        float ih = fminf(sy2, c.w) - fmaxf(sy1, c.z);
        float inter = fmaxf(iw, 0.0f) * fmaxf(ih, 0.0f);
        float uni = sarea + t0.z * t0.w - inter + EPSV;
        float iou = inter / uni;
        float cw = fmaxf(sx2, c.y) - fminf(sx1, c.x);
        float ch = fmaxf(sy2, c.w) - fminf(sy1, c.z);
        float carea = cw * ch + EPSV;
        float giou1 = 1.0f - (iou - (carea - uni) / carea);
        float l1 = fabsf(sb.x - t0.x) + fabsf(sb.y - t0.y) +
                   fabsf(sb.z - t0.z) + fabsf(sb.w - t0.w);
        float v = 0.0f;
        if (sconf0 > 0.0f && best > IOU_THR) v = 5.0f * l1 + 2.0f * giou1;
        g_v[o] = v;
    }
    __syncthreads();

    // ---- BCE + conf: 16-lane group per row; float4 + scalar loads ----
    const int wv  = tid >> 6, lane = tid & 63;
    const int grp = lane >> 4, tc2 = lane & 15;
    const int s2  = wv * 4 + grp;              // 0..15
    const int sq2 = bx * SPB + s2;
    if (sq2 < NQ) {
        int row = b * NQ + sq2;
        int j   = lidx[s2];                    // flat idx -> batch-0 teacher row (ref quirk)
        const float* srow = s_logits + row * NC;
        const float* trow = t_logits + row * NC;
        const float* grow = t_logits + j * NC;
        float4 svv = *(const float4*)(srow + tc2 * 4);
        float4 tvv = *(const float4*)(trow + tc2 * 4);
        float4 gvv = *(const float4*)(grow + tc2 * 4);
        float  s4 = srow[64 + tc2];
        float  t4 = trow[64 + tc2];
        float  g4 = grow[64 + tc2];
        float bce = 0.f;
        {
            float se[5] = {svv.x, svv.y, svv.z, svv.w, s4};
            float ge[5] = {gvv.x, gvv.y, gvv.z, gvv.w, g4};
            #pragma unroll
            for (int e = 0; e < 5; ++e) {
                float s0 = se[e], g0 = ge[e];
                bce += fmaxf(s0, 0.f) + __logf(1.0f + __expf(-fabsf(s0)))
                     - s0 * __builtin_amdgcn_rcpf(1.0f + __expf(-g0));
            }
        }
        float tmax = fmaxf(fmaxf(fmaxf(tvv.x, tvv.y), fmaxf(tvv.z, tvv.w)), t4);
        for (int m = 8; m >= 1; m >>= 1) {
            bce  += __shfl_xor(bce, m, 64);
            tmax  = fmaxf(tmax, __shfl_xor(tmax, m, 64));
        }
        if (tc2 == 0)
            sres[s2] = make_float2(bce * (1.0f / (float)NC),
                                   (sigm(tmax) > 0.2f) ? 1.0f : 0.0f);
    }
    __syncthreads();
    if (tid < 64) {
        float bs = 0.f, ca = 0.f;
        if (tid < SPB) { float2 p = sres[tid]; bs = p.x; ca = p.y; }
        for (int m = 32; m >= 1; m >>= 1) {
            bs += __shfl_xor(bs, m, 64);
            ca  = fmaxf(ca, __shfl_xor(ca, m, 64));
        }
        if (tid == 0) g_part[b * CHB + bx] = make_float2(bs, ca);
    }
}

// ---- K2: 17 blocks — per-batch LDS histogram + cnt·v dot; block 16 reduces g_part ----
__global__ __launch_bounds__(256) void k_mid(
    const int*    __restrict__ g_idx,
    const float*  __restrict__ g_v,
    const float2* __restrict__ g_part,
    float2*       __restrict__ vpart)   // [17]: b<16 -> (vs_b, 0); 16 -> (bce, conf)
{
    const int bb  = blockIdx.x;
    const int tid = threadIdx.x;
    const int wv = tid >> 6, lane = tid & 63;
    if (bb < NB) {
        __shared__ int   cnt[NQ];      // 3.6 KB
        __shared__ float rw[4];
        for (int i = tid; i < NQ; i += 256) cnt[i] = 0;
        __syncthreads();
        for (int i = tid; i < NQ; i += 256)
            atomicAdd(&cnt[g_idx[bb * NQ + i]], 1);     // LDS atomic, deterministic
        __syncthreads();
        float vs = 0.f;
        for (int i = tid; i < NQ; i += 256)
            vs += (float)cnt[i] * g_v[bb * NQ + i];     // coalesced, fixed order
        for (int m = 32; m >= 1; m >>= 1) vs += __shfl_xor(vs, m, 64);
        if (lane == 0) rw[wv] = vs;
        __syncthreads();
        if (tid == 0) vpart[bb] = make_float2(rw[0] + rw[1] + rw[2] + rw[3], 0.f);
    } else {
        __shared__ float rb[4], rc[4];
        float bs = 0.f, ca = 0.f;
        for (int i = tid; i < NBLK; i += 256) {
            float2 p = g_part[i];
            bs += p.x; ca = fmaxf(ca, p.y);
        }
        for (int m = 32; m >= 1; m >>= 1) {
            bs += __shfl_xor(bs, m, 64);
            ca  = fmaxf(ca, __shfl_xor(ca, m, 64));
        }
        if (lane == 0) { rb[wv] = bs; rc[wv] = ca; }
        __syncthreads();
        if (tid == 0)
            vpart[16] = make_float2(rb[0] + rb[1] + rb[2] + rb[3],
                                    fmaxf(fmaxf(rc[0], rc[1]), fmaxf(rc[2], rc[3])));
    }
}

// ---- K3: one wave — combine 16 batch partials + finalize ----
__global__ __launch_bounds__(64) void k_tiny(
    const float2* __restrict__ vpart,
    const int*    __restrict__ tn_p,
    float* __restrict__ out)
{
    const int lane = threadIdx.x;
    float px = (lane < NB) ? vpart[lane].x : 0.f;
    for (int m = 8; m >= 1; m >>= 1) px += __shfl_xor(px, m, 64);  // lanes 0-15 sum
    if (lane == 0) {
        float2 pc = vpart[16];               // (bce_sum, conf_any)
        float tn = (float)tn_p[0];
        out[0] = (pc.y > 0.f) ? (px + pc.x) / tn : 0.0f;
    }
}

extern "C" void kernel_launch(void* const* d_in, const int* in_sizes, int n_in,
                              void* d_out, int out_size, void* d_ws, size_t ws_size,
                              hipStream_t stream) {
    const float* s_logits = (const float*)d_in[0];
    const float* s_boxes  = (const float*)d_in[1];
    const float* t_logits = (const float*)d_in[2];
    const float* t_boxes  = (const float*)d_in[3];
    const int*   tn       = (const int*)d_in[4];
    float* out = (float*)d_out;

    char* ws = (char*)d_ws;
    int*    g_idx  = (int*)(ws);              // 14400 i32
    float*  g_v    = (float*)(ws + 57600);    // 14400 f32
    float2* g_part = (float2*)(ws + 115200);  // 912 float2
    float2* vpart  = (float2*)(ws + 122496);  // 17 float2

    k_main<<<dim3(CHB, NB), 256, 0, stream>>>(s_logits, s_boxes, t_logits, t_boxes,
                                              g_idx, g_v, g_part);
    k_mid<<<NB + 1, 256, 0, stream>>>(g_idx, g_v, g_part, vpart);
    k_tiny<<<1, 64, 0, stream>>>(vpart, tn, out);
}